// Round 1
// baseline (702.413 us; speedup 1.0000x reference)
//
#include <hip/hip_runtime.h>

#define N_NODES 100000
#define N_EDGES 1600000
#define K_DIM   200
#define C_DIM   64
#define EPS_BN  1e-5f

// ---------------- degree count (edges only; self-loop added as +1 later) ----
__global__ void k_deg(const int* __restrict__ dst, float* __restrict__ deg) {
    int tid = blockIdx.x * blockDim.x + threadIdx.x;
    int stride = gridDim.x * blockDim.x;
    for (int e = tid; e < N_EDGES; e += stride)
        unsafeAtomicAdd(&deg[dst[e]], 1.0f);
}

// ---------------- dinv = rsqrt(deg + 1) in place ---------------------------
__global__ void k_dinv(float* __restrict__ deg) {
    int i = blockIdx.x * blockDim.x + threadIdx.x;
    if (i < N_NODES) deg[i] = rsqrtf(deg[i] + 1.0f);
}

// ---------------- xw = x @ W  (W staged in LDS, 1 wave = 4 rows/iter) ------
__global__ void k_gemm(const float* __restrict__ x, const float* __restrict__ W,
                       float* __restrict__ xw) {
    __shared__ float Wl[K_DIM * C_DIM];   // 51.2 KB
    for (int i = threadIdx.x; i < K_DIM * C_DIM; i += blockDim.x)
        Wl[i] = W[i];
    __syncthreads();

    int lane = threadIdx.x & 63;
    int wave = (blockIdx.x * blockDim.x + threadIdx.x) >> 6;
    int nw   = (gridDim.x * blockDim.x) >> 6;

    for (int r0 = wave * 4; r0 < N_NODES; r0 += nw * 4) {  // N_NODES % 4 == 0
        const float* xp = x + (size_t)r0 * K_DIM;
        float a0 = 0.f, a1 = 0.f, a2 = 0.f, a3 = 0.f;
        for (int k = 0; k < K_DIM; k += 4) {
            float4 v0 = *(const float4*)(xp + k);
            float4 v1 = *(const float4*)(xp + K_DIM + k);
            float4 v2 = *(const float4*)(xp + 2 * K_DIM + k);
            float4 v3 = *(const float4*)(xp + 3 * K_DIM + k);
            float w0 = Wl[(k + 0) * C_DIM + lane];
            float w1 = Wl[(k + 1) * C_DIM + lane];
            float w2 = Wl[(k + 2) * C_DIM + lane];
            float w3 = Wl[(k + 3) * C_DIM + lane];
            a0 = fmaf(v0.x, w0, fmaf(v0.y, w1, fmaf(v0.z, w2, fmaf(v0.w, w3, a0))));
            a1 = fmaf(v1.x, w0, fmaf(v1.y, w1, fmaf(v1.z, w2, fmaf(v1.w, w3, a1))));
            a2 = fmaf(v2.x, w0, fmaf(v2.y, w1, fmaf(v2.z, w2, fmaf(v2.w, w3, a2))));
            a3 = fmaf(v3.x, w0, fmaf(v3.y, w1, fmaf(v3.z, w2, fmaf(v3.w, w3, a3))));
        }
        xw[(r0 + 0) * C_DIM + lane] = a0;
        xw[(r0 + 1) * C_DIM + lane] = a1;
        xw[(r0 + 2) * C_DIM + lane] = a2;
        xw[(r0 + 3) * C_DIM + lane] = a3;
    }
}

// ---------------- edge scatter: agg[dst] += dinv[s]*dinv[d] * xw[src] ------
__global__ void k_scatter(const int* __restrict__ src, const int* __restrict__ dst,
                          const float* __restrict__ dinv, const float* __restrict__ xw,
                          float* __restrict__ agg) {
    int tid = blockIdx.x * blockDim.x + threadIdx.x;
    int stride = gridDim.x * blockDim.x;
    int c = tid & 63;
    for (int i = tid; i < N_EDGES * C_DIM; i += stride) {
        int e = i >> 6;
        int s = src[e];
        int d = dst[e];
        float nrm = dinv[s] * dinv[d];
        unsafeAtomicAdd(&agg[d * C_DIM + c], nrm * xw[s * C_DIM + c]);
    }
}

// ---------------- self-loop + bias + relu + BN stats (h in place) ----------
__global__ void k_bnstats(float* __restrict__ agg, const float* __restrict__ xw,
                          const float* __restrict__ dinv, const float* __restrict__ b,
                          float* __restrict__ stats) {
    int tid = blockIdx.x * blockDim.x + threadIdx.x;
    int stride = gridDim.x * blockDim.x;   // multiple of 64 -> channel fixed
    int c = tid & 63;
    float bc = b[c];
    float s = 0.f, s2 = 0.f;
    for (int i = tid; i < N_NODES * C_DIM; i += stride) {
        int n = i >> 6;
        float di = dinv[n];
        float h = agg[i] + di * di * xw[i] + bc;
        h = fmaxf(h, 0.f);
        agg[i] = h;
        s += h;
        s2 += h * h;
    }
    __shared__ float ls[256], ls2[256];
    ls[threadIdx.x] = s;
    ls2[threadIdx.x] = s2;
    __syncthreads();
    if (threadIdx.x < 64) {
        float t  = ls[threadIdx.x] + ls[threadIdx.x + 64] + ls[threadIdx.x + 128] + ls[threadIdx.x + 192];
        float t2 = ls2[threadIdx.x] + ls2[threadIdx.x + 64] + ls2[threadIdx.x + 128] + ls2[threadIdx.x + 192];
        unsafeAtomicAdd(&stats[threadIdx.x], t);
        unsafeAtomicAdd(&stats[64 + threadIdx.x], t2);
    }
}

// ---------------- BN apply -------------------------------------------------
__global__ void k_final(const float* __restrict__ h, const float* __restrict__ stats,
                        const float* __restrict__ bnw, const float* __restrict__ bnb,
                        float* __restrict__ out) {
    int tid = blockIdx.x * blockDim.x + threadIdx.x;
    int stride = gridDim.x * blockDim.x;
    int c = tid & 63;
    float mean  = stats[c] * (1.0f / N_NODES);
    float var   = stats[64 + c] * (1.0f / N_NODES) - mean * mean;
    float scale = rsqrtf(var + EPS_BN) * bnw[c];
    float shift = bnb[c] - mean * scale;
    for (int i = tid; i < N_NODES * C_DIM; i += stride)
        out[i] = fmaf(h[i], scale, shift);
}

// ---------------------------------------------------------------------------
extern "C" void kernel_launch(void* const* d_in, const int* in_sizes, int n_in,
                              void* d_out, int out_size, void* d_ws, size_t ws_size,
                              hipStream_t stream) {
    const float* x   = (const float*)d_in[0];
    const int*   ei  = (const int*)d_in[1];
    const float* W   = (const float*)d_in[2];
    const float* b   = (const float*)d_in[3];
    const float* bnw = (const float*)d_in[4];
    const float* bnb = (const float*)d_in[5];
    float* out = (float*)d_out;

    const int* src = ei;
    const int* dst = ei + N_EDGES;

    // workspace layout (zeroed region is contiguous: deg | agg | stats)
    char* ws = (char*)d_ws;
    const size_t DEG_BYTES = 400128;                 // 100000*4 padded to 256B
    const size_t AGG_BYTES = (size_t)N_NODES * C_DIM * 4;  // 25.6 MB
    float* deg   = (float*)ws;                       // becomes dinv in place
    float* agg   = (float*)(ws + DEG_BYTES);
    float* stats = (float*)(ws + DEG_BYTES + AGG_BYTES);
    const size_t ZERO_BYTES = DEG_BYTES + AGG_BYTES + 512;

    // xw lives in d_out (dead after k_bnstats, then overwritten by k_final)
    float* xw = out;

    hipMemsetAsync(d_ws, 0, ZERO_BYTES, stream);

    k_deg<<<2048, 256, 0, stream>>>(dst, deg);
    k_dinv<<<(N_NODES + 255) / 256, 256, 0, stream>>>(deg);
    k_gemm<<<1024, 256, 0, stream>>>(x, W, xw);
    k_scatter<<<4096, 256, 0, stream>>>(src, dst, deg, xw, agg);
    k_bnstats<<<2048, 256, 0, stream>>>(agg, xw, deg, b, stats);
    k_final<<<2048, 256, 0, stream>>>(agg, stats, bnw, bnb, out);
}

// Round 2
// 533.893 us; speedup vs baseline: 1.3156x; 1.3156x over previous
//
#include <hip/hip_runtime.h>

#define N_NODES 100000
#define N_EDGES 1600000
#define K_DIM   200
#define C_DIM   64
#define EPS_BN  1e-5f
#define NB_SCAN ((N_NODES + 255) / 256)   // 391

// ===================== shared kernels =====================================

// ---------------- xw = x @ W  (W staged in LDS, 1 wave = 4 rows/iter) ------
__global__ void k_gemm(const float* __restrict__ x, const float* __restrict__ W,
                       float* __restrict__ xw) {
    __shared__ float Wl[K_DIM * C_DIM];   // 51.2 KB
    for (int i = threadIdx.x; i < K_DIM * C_DIM; i += blockDim.x)
        Wl[i] = W[i];
    __syncthreads();

    int lane = threadIdx.x & 63;
    int wave = (blockIdx.x * blockDim.x + threadIdx.x) >> 6;
    int nw   = (gridDim.x * blockDim.x) >> 6;

    for (int r0 = wave * 4; r0 < N_NODES; r0 += nw * 4) {  // N_NODES % 4 == 0
        const float* xp = x + (size_t)r0 * K_DIM;
        float a0 = 0.f, a1 = 0.f, a2 = 0.f, a3 = 0.f;
        for (int k = 0; k < K_DIM; k += 4) {
            float4 v0 = *(const float4*)(xp + k);
            float4 v1 = *(const float4*)(xp + K_DIM + k);
            float4 v2 = *(const float4*)(xp + 2 * K_DIM + k);
            float4 v3 = *(const float4*)(xp + 3 * K_DIM + k);
            float w0 = Wl[(k + 0) * C_DIM + lane];
            float w1 = Wl[(k + 1) * C_DIM + lane];
            float w2 = Wl[(k + 2) * C_DIM + lane];
            float w3 = Wl[(k + 3) * C_DIM + lane];
            a0 = fmaf(v0.x, w0, fmaf(v0.y, w1, fmaf(v0.z, w2, fmaf(v0.w, w3, a0))));
            a1 = fmaf(v1.x, w0, fmaf(v1.y, w1, fmaf(v1.z, w2, fmaf(v1.w, w3, a1))));
            a2 = fmaf(v2.x, w0, fmaf(v2.y, w1, fmaf(v2.z, w2, fmaf(v2.w, w3, a2))));
            a3 = fmaf(v3.x, w0, fmaf(v3.y, w1, fmaf(v3.z, w2, fmaf(v3.w, w3, a3))));
        }
        xw[(r0 + 0) * C_DIM + lane] = a0;
        xw[(r0 + 1) * C_DIM + lane] = a1;
        xw[(r0 + 2) * C_DIM + lane] = a2;
        xw[(r0 + 3) * C_DIM + lane] = a3;
    }
}

// ---------------- BN apply -------------------------------------------------
__global__ void k_final(const float* __restrict__ h, const float* __restrict__ stats,
                        const float* __restrict__ bnw, const float* __restrict__ bnb,
                        float* __restrict__ out) {
    int tid = blockIdx.x * blockDim.x + threadIdx.x;
    int stride = gridDim.x * blockDim.x;
    int c = tid & 63;
    float mean  = stats[c] * (1.0f / N_NODES);
    float var   = stats[64 + c] * (1.0f / N_NODES) - mean * mean;
    float scale = rsqrtf(var + EPS_BN) * bnw[c];
    float shift = bnb[c] - mean * scale;
    for (int i = tid; i < N_NODES * C_DIM; i += stride)
        out[i] = fmaf(h[i], scale, shift);
}

// ===================== CSR path ===========================================

__global__ void k_deg_int(const int* __restrict__ dst, int* __restrict__ deg) {
    int tid = blockIdx.x * blockDim.x + threadIdx.x;
    int stride = gridDim.x * blockDim.x;
    for (int e = tid; e < N_EDGES; e += stride)
        atomicAdd(&deg[dst[e]], 1);
}

__global__ void k_scan_block(const int* __restrict__ deg, int* __restrict__ bsum) {
    __shared__ int ls[256];
    int i = blockIdx.x * 256 + threadIdx.x;
    ls[threadIdx.x] = (i < N_NODES) ? deg[i] : 0;
    __syncthreads();
    for (int off = 128; off > 0; off >>= 1) {
        if (threadIdx.x < off) ls[threadIdx.x] += ls[threadIdx.x + off];
        __syncthreads();
    }
    if (threadIdx.x == 0) bsum[blockIdx.x] = ls[0];
}

__global__ void k_scan_top(const int* __restrict__ bsum, int* __restrict__ boff) {
    __shared__ int ls[512];
    int v = (threadIdx.x < NB_SCAN) ? bsum[threadIdx.x] : 0;
    ls[threadIdx.x] = v;
    __syncthreads();
    for (int off = 1; off < 512; off <<= 1) {
        int t = (threadIdx.x >= off) ? ls[threadIdx.x - off] : 0;
        __syncthreads();
        ls[threadIdx.x] += t;
        __syncthreads();
    }
    if (threadIdx.x < NB_SCAN) boff[threadIdx.x] = ls[threadIdx.x] - v; // exclusive
}

__global__ void k_scan_write(const int* __restrict__ deg, const int* __restrict__ boff,
                             int* __restrict__ row_start, float* __restrict__ dinv) {
    __shared__ int ls[256];
    int i = blockIdx.x * 256 + threadIdx.x;
    int v = (i < N_NODES) ? deg[i] : 0;
    ls[threadIdx.x] = v;
    __syncthreads();
    for (int off = 1; off < 256; off <<= 1) {        // inclusive scan
        int t = (threadIdx.x >= off) ? ls[threadIdx.x - off] : 0;
        __syncthreads();
        ls[threadIdx.x] += t;
        __syncthreads();
    }
    if (i < N_NODES) {
        row_start[i] = boff[blockIdx.x] + ls[threadIdx.x] - v;  // exclusive
        dinv[i] = rsqrtf((float)v + 1.0f);                      // +1 self loop
    }
    if (i == N_NODES - 1) row_start[N_NODES] = N_EDGES;
}

__global__ void k_fill(const int* __restrict__ src, const int* __restrict__ dst,
                       const int* __restrict__ row_start, int* __restrict__ cursor,
                       int* __restrict__ csr) {
    int tid = blockIdx.x * blockDim.x + threadIdx.x;
    int stride = gridDim.x * blockDim.x;
    for (int e = tid; e < N_EDGES; e += stride) {
        int d = dst[e];
        int pos = atomicAdd(&cursor[d], 1);
        csr[row_start[d] + pos] = src[e];
    }
}

// gather + self-loop + bias + relu + BN stats, atomic-free aggregation
__global__ void k_gather(const int* __restrict__ csr, const int* __restrict__ row_start,
                         const float* __restrict__ dinv, const float* __restrict__ xw,
                         const float* __restrict__ b, float* __restrict__ h,
                         float* __restrict__ stats) {
    int lane = threadIdx.x & 63;
    int wid  = (blockIdx.x * blockDim.x + threadIdx.x) >> 6;
    int nw   = (gridDim.x * blockDim.x) >> 6;
    float bc = b[lane];
    float s1 = 0.f, s2 = 0.f;

    for (int node = wid; node < N_NODES; node += nw) {
        int beg = row_start[node], end = row_start[node + 1];
        float acc = 0.f;
        for (int j0 = beg; j0 < end; j0 += 64) {
            int myc = 0; float mydv = 0.f;
            if (j0 + lane < end) { myc = csr[j0 + lane]; mydv = dinv[myc]; }
            int lim = end - j0; if (lim > 64) lim = 64;
            for (int j = 0; j < lim; ++j) {
                int   s  = __shfl(myc, j);
                float dv = __shfl(mydv, j);
                acc = fmaf(dv, xw[(size_t)s * C_DIM + lane], acc);
            }
        }
        float dn = dinv[node];
        acc += dn * xw[(size_t)node * C_DIM + lane];   // self loop
        float hv = fmaf(dn, acc, bc);
        hv = fmaxf(hv, 0.f);
        h[(size_t)node * C_DIM + lane] = hv;
        s1 += hv; s2 += hv * hv;
    }

    __shared__ float l1[256], l2[256];
    l1[threadIdx.x] = s1; l2[threadIdx.x] = s2;
    __syncthreads();
    if (threadIdx.x < 64) {
        float t1 = l1[threadIdx.x] + l1[threadIdx.x + 64] + l1[threadIdx.x + 128] + l1[threadIdx.x + 192];
        float t2 = l2[threadIdx.x] + l2[threadIdx.x + 64] + l2[threadIdx.x + 128] + l2[threadIdx.x + 192];
        unsafeAtomicAdd(&stats[threadIdx.x], t1);
        unsafeAtomicAdd(&stats[64 + threadIdx.x], t2);
    }
}

// ===================== fallback (R1 atomic-scatter) path ==================

__global__ void k_deg_f(const int* __restrict__ dst, float* __restrict__ deg) {
    int tid = blockIdx.x * blockDim.x + threadIdx.x;
    int stride = gridDim.x * blockDim.x;
    for (int e = tid; e < N_EDGES; e += stride)
        unsafeAtomicAdd(&deg[dst[e]], 1.0f);
}

__global__ void k_dinv_f(float* __restrict__ deg) {
    int i = blockIdx.x * blockDim.x + threadIdx.x;
    if (i < N_NODES) deg[i] = rsqrtf(deg[i] + 1.0f);
}

__global__ void k_scatter(const int* __restrict__ src, const int* __restrict__ dst,
                          const float* __restrict__ dinv, const float* __restrict__ xw,
                          float* __restrict__ agg) {
    int tid = blockIdx.x * blockDim.x + threadIdx.x;
    int stride = gridDim.x * blockDim.x;
    int c = tid & 63;
    for (int i = tid; i < N_EDGES * C_DIM; i += stride) {
        int e = i >> 6;
        int s = src[e];
        int d = dst[e];
        float nrm = dinv[s] * dinv[d];
        unsafeAtomicAdd(&agg[d * C_DIM + c], nrm * xw[s * C_DIM + c]);
    }
}

__global__ void k_bnstats(float* __restrict__ agg, const float* __restrict__ xw,
                          const float* __restrict__ dinv, const float* __restrict__ b,
                          float* __restrict__ stats) {
    int tid = blockIdx.x * blockDim.x + threadIdx.x;
    int stride = gridDim.x * blockDim.x;
    int c = tid & 63;
    float bc = b[c];
    float s = 0.f, s2 = 0.f;
    for (int i = tid; i < N_NODES * C_DIM; i += stride) {
        int n = i >> 6;
        float di = dinv[n];
        float hh = agg[i] + di * di * xw[i] + bc;
        hh = fmaxf(hh, 0.f);
        agg[i] = hh;
        s += hh;
        s2 += hh * hh;
    }
    __shared__ float ls[256], ls2[256];
    ls[threadIdx.x] = s;
    ls2[threadIdx.x] = s2;
    __syncthreads();
    if (threadIdx.x < 64) {
        float t  = ls[threadIdx.x] + ls[threadIdx.x + 64] + ls[threadIdx.x + 128] + ls[threadIdx.x + 192];
        float t2 = ls2[threadIdx.x] + ls2[threadIdx.x + 64] + ls2[threadIdx.x + 128] + ls2[threadIdx.x + 192];
        unsafeAtomicAdd(&stats[threadIdx.x], t);
        unsafeAtomicAdd(&stats[64 + threadIdx.x], t2);
    }
}

// ===========================================================================
extern "C" void kernel_launch(void* const* d_in, const int* in_sizes, int n_in,
                              void* d_out, int out_size, void* d_ws, size_t ws_size,
                              hipStream_t stream) {
    const float* x   = (const float*)d_in[0];
    const int*   ei  = (const int*)d_in[1];
    const float* W   = (const float*)d_in[2];
    const float* b   = (const float*)d_in[3];
    const float* bnw = (const float*)d_in[4];
    const float* bnb = (const float*)d_in[5];
    float* out = (float*)d_out;

    const int* src = ei;
    const int* dst = ei + N_EDGES;
    char* ws = (char*)d_ws;

    const size_t SZ_I = 400128;                 // 100000*4 padded
    // CSR layout: [deg_int][cursor][stats(512B)][dinv][row_start][bsum(2K)][boff(2K)][csr 6.4M][h 25.6M]
    const size_t OFF_CUR  = SZ_I;
    const size_t OFF_STAT = 2 * SZ_I;
    const size_t OFF_DINV = 2 * SZ_I + 512;
    const size_t OFF_ROW  = 3 * SZ_I + 512;
    const size_t OFF_BSUM = 4 * SZ_I + 512;
    const size_t OFF_BOFF = 4 * SZ_I + 2560;
    const size_t OFF_CSR  = 4 * SZ_I + 4608;
    const size_t OFF_H    = OFF_CSR + (size_t)N_EDGES * 4;
    const size_t NEEDED   = OFF_H + (size_t)N_NODES * C_DIM * 4;

    float* xw = out;   // xw lives in d_out until k_final overwrites it

    if (ws_size >= NEEDED) {
        int*   deg       = (int*)ws;
        int*   cursor    = (int*)(ws + OFF_CUR);
        float* stats     = (float*)(ws + OFF_STAT);
        float* dinv      = (float*)(ws + OFF_DINV);
        int*   row_start = (int*)(ws + OFF_ROW);
        int*   bsum      = (int*)(ws + OFF_BSUM);
        int*   boff      = (int*)(ws + OFF_BOFF);
        int*   csr       = (int*)(ws + OFF_CSR);
        float* h         = (float*)(ws + OFF_H);

        hipMemsetAsync(d_ws, 0, OFF_STAT + 512, stream);  // deg, cursor, stats

        k_deg_int  <<<2048, 256, 0, stream>>>(dst, deg);
        k_scan_block<<<NB_SCAN, 256, 0, stream>>>(deg, bsum);
        k_scan_top <<<1, 512, 0, stream>>>(bsum, boff);
        k_scan_write<<<NB_SCAN, 256, 0, stream>>>(deg, boff, row_start, dinv);
        k_fill     <<<2048, 256, 0, stream>>>(src, dst, row_start, cursor, csr);
        k_gemm     <<<1024, 256, 0, stream>>>(x, W, xw);
        k_gather   <<<2048, 256, 0, stream>>>(csr, row_start, dinv, xw, b, h, stats);
        k_final    <<<2048, 256, 0, stream>>>(h, stats, bnw, bnb, out);
    } else {
        // R1 fallback: atomic scatter
        const size_t DEG_BYTES = SZ_I;
        const size_t AGG_BYTES = (size_t)N_NODES * C_DIM * 4;
        float* deg   = (float*)ws;
        float* agg   = (float*)(ws + DEG_BYTES);
        float* stats = (float*)(ws + DEG_BYTES + AGG_BYTES);

        hipMemsetAsync(d_ws, 0, DEG_BYTES + AGG_BYTES + 512, stream);
        k_deg_f  <<<2048, 256, 0, stream>>>(dst, deg);
        k_dinv_f <<<(N_NODES + 255) / 256, 256, 0, stream>>>(deg);
        k_gemm   <<<1024, 256, 0, stream>>>(x, W, xw);
        k_scatter<<<4096, 256, 0, stream>>>(src, dst, deg, xw, agg);
        k_bnstats<<<2048, 256, 0, stream>>>(agg, xw, deg, b, stats);
        k_final  <<<2048, 256, 0, stream>>>(agg, stats, bnw, bnb, out);
    }
}

// Round 3
// 478.799 us; speedup vs baseline: 1.4670x; 1.1151x over previous
//
#include <hip/hip_runtime.h>

#define N_NODES 100000
#define N_EDGES 1600000
#define K_DIM   200
#define C_DIM   64
#define EPS_BN  1e-5f
#define NB_SCAN ((N_NODES + 255) / 256)   // 391
#define MT      128                       // gemm rows per block
#define NKB     25                        // 200 / 8 k-blocks

// ===================== GEMM: register-tiled, 128x64 block tile =============
__global__ __launch_bounds__(256) void k_gemm2(const float* __restrict__ x,
                                               const float* __restrict__ W,
                                               float* __restrict__ xw) {
    __shared__ float xT[8][MT];      // 4 KB, transposed x tile
    __shared__ float Wt[8][C_DIM];   // 2 KB
    int tid = threadIdx.x;
    int tx = tid & 15;               // col quad: c0 = tx*4
    int ty = tid >> 4;               // row octet: r0 = ty*8
    int row0 = blockIdx.x * MT;

    // staging assignment: thread -> (row, k-half)
    int lrow = tid >> 1;             // 0..127
    int lk   = (tid & 1) * 4;        // 0 or 4
    int grow = row0 + lrow;
    if (grow > N_NODES - 1) grow = N_NODES - 1;   // clamp for tail block
    const float* xp = x + (size_t)grow * K_DIM + lk;
    int wk = tid >> 4;               // W staging (tid<128): k row 0..7
    int wc = (tid & 15) * 4;         // col quad

    float acc[8][4];
    #pragma unroll
    for (int i = 0; i < 8; ++i)
        #pragma unroll
        for (int j = 0; j < 4; ++j) acc[i][j] = 0.f;

    float4 xr = *(const float4*)xp;
    float4 wr = {0,0,0,0};
    if (tid < 128) wr = *(const float4*)(W + wk * C_DIM + wc);

    for (int kb = 0; kb < NKB; ++kb) {
        xT[lk + 0][lrow] = xr.x;
        xT[lk + 1][lrow] = xr.y;
        xT[lk + 2][lrow] = xr.z;
        xT[lk + 3][lrow] = xr.w;
        if (tid < 128) *(float4*)&Wt[wk][wc] = wr;
        __syncthreads();
        if (kb < NKB - 1) {                       // prefetch next tiles
            xr = *(const float4*)(xp + (kb + 1) * 8);
            if (tid < 128) wr = *(const float4*)(W + ((kb + 1) * 8 + wk) * C_DIM + wc);
        }
        #pragma unroll
        for (int k = 0; k < 8; ++k) {
            float4 xa = *(const float4*)&xT[k][ty * 8];
            float4 xb = *(const float4*)&xT[k][ty * 8 + 4];
            float4 wv = *(const float4*)&Wt[k][tx * 4];
            float xv[8] = {xa.x, xa.y, xa.z, xa.w, xb.x, xb.y, xb.z, xb.w};
            #pragma unroll
            for (int i = 0; i < 8; ++i) {
                acc[i][0] = fmaf(xv[i], wv.x, acc[i][0]);
                acc[i][1] = fmaf(xv[i], wv.y, acc[i][1]);
                acc[i][2] = fmaf(xv[i], wv.z, acc[i][2]);
                acc[i][3] = fmaf(xv[i], wv.w, acc[i][3]);
            }
        }
        __syncthreads();
    }
    #pragma unroll
    for (int i = 0; i < 8; ++i) {
        int r = row0 + ty * 8 + i;
        if (r < N_NODES) {
            float4 o = {acc[i][0], acc[i][1], acc[i][2], acc[i][3]};
            *(float4*)(xw + (size_t)r * C_DIM + tx * 4) = o;
        }
    }
}

// ---------------- BN apply, float4 ----------------------------------------
__global__ void k_final4(const float4* __restrict__ h4, const float* __restrict__ stats,
                         const float* __restrict__ bnw, const float* __restrict__ bnb,
                         float4* __restrict__ out4) {
    int tid = blockIdx.x * blockDim.x + threadIdx.x;
    int stride = gridDim.x * blockDim.x;   // multiple of 16 -> q fixed
    int q = tid & 15;
    float4 scale, shift;
    {
        float s[4], f[4];
        #pragma unroll
        for (int j = 0; j < 4; ++j) {
            int c = q * 4 + j;
            float mean = stats[c] * (1.0f / N_NODES);
            float var  = stats[64 + c] * (1.0f / N_NODES) - mean * mean;
            s[j] = rsqrtf(var + EPS_BN) * bnw[c];
            f[j] = bnb[c] - mean * s[j];
        }
        scale = {s[0], s[1], s[2], s[3]};
        shift = {f[0], f[1], f[2], f[3]};
    }
    for (int i = tid; i < N_NODES * 16; i += stride) {
        float4 h = h4[i];
        float4 o;
        o.x = fmaf(h.x, scale.x, shift.x);
        o.y = fmaf(h.y, scale.y, shift.y);
        o.z = fmaf(h.z, scale.z, shift.z);
        o.w = fmaf(h.w, scale.w, shift.w);
        out4[i] = o;
    }
}

// ===================== CSR build ==========================================
__global__ void k_deg_int(const int* __restrict__ dst, int* __restrict__ deg) {
    int tid = blockIdx.x * blockDim.x + threadIdx.x;
    int stride = gridDim.x * blockDim.x;
    for (int e = tid; e < N_EDGES; e += stride)
        atomicAdd(&deg[dst[e]], 1);
}

__global__ void k_scan_block(const int* __restrict__ deg, int* __restrict__ bsum) {
    __shared__ int ls[256];
    int i = blockIdx.x * 256 + threadIdx.x;
    ls[threadIdx.x] = (i < N_NODES) ? deg[i] : 0;
    __syncthreads();
    for (int off = 128; off > 0; off >>= 1) {
        if (threadIdx.x < off) ls[threadIdx.x] += ls[threadIdx.x + off];
        __syncthreads();
    }
    if (threadIdx.x == 0) bsum[blockIdx.x] = ls[0];
}

__global__ void k_scan_top(const int* __restrict__ bsum, int* __restrict__ boff) {
    __shared__ int ls[512];
    int v = (threadIdx.x < NB_SCAN) ? bsum[threadIdx.x] : 0;
    ls[threadIdx.x] = v;
    __syncthreads();
    for (int off = 1; off < 512; off <<= 1) {
        int t = (threadIdx.x >= off) ? ls[threadIdx.x - off] : 0;
        __syncthreads();
        ls[threadIdx.x] += t;
        __syncthreads();
    }
    if (threadIdx.x < NB_SCAN) boff[threadIdx.x] = ls[threadIdx.x] - v; // exclusive
}

__global__ void k_scan_write(const int* __restrict__ deg, const int* __restrict__ boff,
                             int* __restrict__ row_start, float* __restrict__ dinv) {
    __shared__ int ls[256];
    int i = blockIdx.x * 256 + threadIdx.x;
    int v = (i < N_NODES) ? deg[i] : 0;
    ls[threadIdx.x] = v;
    __syncthreads();
    for (int off = 1; off < 256; off <<= 1) {        // inclusive scan
        int t = (threadIdx.x >= off) ? ls[threadIdx.x - off] : 0;
        __syncthreads();
        ls[threadIdx.x] += t;
        __syncthreads();
    }
    if (i < N_NODES) {
        row_start[i] = boff[blockIdx.x] + ls[threadIdx.x] - v;  // exclusive
        dinv[i] = rsqrtf((float)v + 1.0f);                      // +1 self loop
    }
    if (i == N_NODES - 1) row_start[N_NODES] = N_EDGES;
}

__global__ void k_fill(const int* __restrict__ src, const int* __restrict__ dst,
                       const int* __restrict__ row_start, int* __restrict__ cursor,
                       int* __restrict__ csr) {
    int tid = blockIdx.x * blockDim.x + threadIdx.x;
    int stride = gridDim.x * blockDim.x;
    for (int e = tid; e < N_EDGES; e += stride) {
        int d = dst[e];
        int pos = atomicAdd(&cursor[d], 1);
        csr[row_start[d] + pos] = src[e];
    }
}

// ===================== gather: 4 neighbors x 64 channels per wave ==========
__global__ void k_gather(const int* __restrict__ csr, const int* __restrict__ row_start,
                         const float* __restrict__ dinv, const float4* __restrict__ xw4,
                         const float* __restrict__ b, float4* __restrict__ h4,
                         float* __restrict__ stats) {
    int tid = threadIdx.x;
    int lane = tid & 63;
    int g = lane >> 4;        // neighbor slot 0..3
    int q = lane & 15;        // channel quad -> channels q*4..q*4+3
    int wid = (blockIdx.x * blockDim.x + tid) >> 6;
    int nw  = (gridDim.x * blockDim.x) >> 6;
    float4 bq = ((const float4*)b)[q];
    float4 s1 = {0,0,0,0}, s2 = {0,0,0,0};

    for (int node = wid; node < N_NODES; node += nw) {
        int beg = row_start[node], end = row_start[node + 1];
        float4 acc = {0,0,0,0};
        for (int j = beg + g; j < end; j += 4) {
            int s = csr[j];                       // 16-lane broadcast
            float dv = dinv[s];
            float4 xv = xw4[(size_t)s * 16 + q];
            acc.x = fmaf(dv, xv.x, acc.x);
            acc.y = fmaf(dv, xv.y, acc.y);
            acc.z = fmaf(dv, xv.z, acc.z);
            acc.w = fmaf(dv, xv.w, acc.w);
        }
        // sum the 4 neighbor groups (lanes differing in bits 4,5)
        acc.x += __shfl_xor(acc.x, 16); acc.y += __shfl_xor(acc.y, 16);
        acc.z += __shfl_xor(acc.z, 16); acc.w += __shfl_xor(acc.w, 16);
        acc.x += __shfl_xor(acc.x, 32); acc.y += __shfl_xor(acc.y, 32);
        acc.z += __shfl_xor(acc.z, 32); acc.w += __shfl_xor(acc.w, 32);

        float dn = dinv[node];
        float4 xs = xw4[(size_t)node * 16 + q];
        float4 hv;
        hv.x = fmaxf(fmaf(dn, fmaf(dn, xs.x, acc.x), bq.x), 0.f);
        hv.y = fmaxf(fmaf(dn, fmaf(dn, xs.y, acc.y), bq.y), 0.f);
        hv.z = fmaxf(fmaf(dn, fmaf(dn, xs.z, acc.z), bq.z), 0.f);
        hv.w = fmaxf(fmaf(dn, fmaf(dn, xs.w, acc.w), bq.w), 0.f);
        if (g == 0) {
            h4[(size_t)node * 16 + q] = hv;
            s1.x += hv.x; s1.y += hv.y; s1.z += hv.z; s1.w += hv.w;
            s2.x = fmaf(hv.x, hv.x, s2.x); s2.y = fmaf(hv.y, hv.y, s2.y);
            s2.z = fmaf(hv.z, hv.z, s2.z); s2.w = fmaf(hv.w, hv.w, s2.w);
        }
    }

    __shared__ float4 l1[256], l2[256];
    l1[tid] = s1; l2[tid] = s2;
    __syncthreads();
    if (tid < 16) {   // tid == q; channels q*4..q*4+3
        float4 a = l1[tid], b1 = l1[tid + 64], c = l1[tid + 128], d = l1[tid + 192];
        float4 e = l2[tid], f = l2[tid + 64], gg = l2[tid + 128], h = l2[tid + 192];
        float t1[4] = {a.x + b1.x + c.x + d.x, a.y + b1.y + c.y + d.y,
                       a.z + b1.z + c.z + d.z, a.w + b1.w + c.w + d.w};
        float t2[4] = {e.x + f.x + gg.x + h.x, e.y + f.y + gg.y + h.y,
                       e.z + f.z + gg.z + h.z, e.w + f.w + gg.w + h.w};
        #pragma unroll
        for (int j = 0; j < 4; ++j) {
            unsafeAtomicAdd(&stats[tid * 4 + j], t1[j]);
            unsafeAtomicAdd(&stats[64 + tid * 4 + j], t2[j]);
        }
    }
}

// ===================== fallback (R1 atomic-scatter) path ==================
__global__ void k_deg_f(const int* __restrict__ dst, float* __restrict__ deg) {
    int tid = blockIdx.x * blockDim.x + threadIdx.x;
    int stride = gridDim.x * blockDim.x;
    for (int e = tid; e < N_EDGES; e += stride)
        unsafeAtomicAdd(&deg[dst[e]], 1.0f);
}

__global__ void k_dinv_f(float* __restrict__ deg) {
    int i = blockIdx.x * blockDim.x + threadIdx.x;
    if (i < N_NODES) deg[i] = rsqrtf(deg[i] + 1.0f);
}

__global__ void k_scatter(const int* __restrict__ src, const int* __restrict__ dst,
                          const float* __restrict__ dinv, const float* __restrict__ xw,
                          float* __restrict__ agg) {
    int tid = blockIdx.x * blockDim.x + threadIdx.x;
    int stride = gridDim.x * blockDim.x;
    int c = tid & 63;
    for (int i = tid; i < N_EDGES * C_DIM; i += stride) {
        int e = i >> 6;
        int s = src[e];
        int d = dst[e];
        float nrm = dinv[s] * dinv[d];
        unsafeAtomicAdd(&agg[d * C_DIM + c], nrm * xw[s * C_DIM + c]);
    }
}

__global__ void k_bnstats(float* __restrict__ agg, const float* __restrict__ xw,
                          const float* __restrict__ dinv, const float* __restrict__ b,
                          float* __restrict__ stats) {
    int tid = blockIdx.x * blockDim.x + threadIdx.x;
    int stride = gridDim.x * blockDim.x;
    int c = tid & 63;
    float bc = b[c];
    float s = 0.f, s2 = 0.f;
    for (int i = tid; i < N_NODES * C_DIM; i += stride) {
        int n = i >> 6;
        float di = dinv[n];
        float hh = agg[i] + di * di * xw[i] + bc;
        hh = fmaxf(hh, 0.f);
        agg[i] = hh;
        s += hh;
        s2 += hh * hh;
    }
    __shared__ float ls[256], ls2[256];
    ls[threadIdx.x] = s;
    ls2[threadIdx.x] = s2;
    __syncthreads();
    if (threadIdx.x < 64) {
        float t  = ls[threadIdx.x] + ls[threadIdx.x + 64] + ls[threadIdx.x + 128] + ls[threadIdx.x + 192];
        float t2 = ls2[threadIdx.x] + ls2[threadIdx.x + 64] + ls2[threadIdx.x + 128] + ls2[threadIdx.x + 192];
        unsafeAtomicAdd(&stats[threadIdx.x], t);
        unsafeAtomicAdd(&stats[64 + threadIdx.x], t2);
    }
}

// ===========================================================================
extern "C" void kernel_launch(void* const* d_in, const int* in_sizes, int n_in,
                              void* d_out, int out_size, void* d_ws, size_t ws_size,
                              hipStream_t stream) {
    const float* x   = (const float*)d_in[0];
    const int*   ei  = (const int*)d_in[1];
    const float* W   = (const float*)d_in[2];
    const float* b   = (const float*)d_in[3];
    const float* bnw = (const float*)d_in[4];
    const float* bnb = (const float*)d_in[5];
    float* out = (float*)d_out;

    const int* src = ei;
    const int* dst = ei + N_EDGES;
    char* ws = (char*)d_ws;

    const size_t SZ_I = 400128;                 // 100000*4 padded
    const size_t OFF_CUR  = SZ_I;
    const size_t OFF_STAT = 2 * SZ_I;
    const size_t OFF_DINV = 2 * SZ_I + 512;
    const size_t OFF_ROW  = 3 * SZ_I + 512;
    const size_t OFF_BSUM = 4 * SZ_I + 512;
    const size_t OFF_BOFF = 4 * SZ_I + 2560;
    const size_t OFF_CSR  = 4 * SZ_I + 4608;
    const size_t OFF_H    = OFF_CSR + (size_t)N_EDGES * 4;
    const size_t NEEDED   = OFF_H + (size_t)N_NODES * C_DIM * 4;

    float* xw = out;   // xw lives in d_out until k_final4 overwrites it
    const int GEMM_GRID = (N_NODES + MT - 1) / MT;   // 782

    if (ws_size >= NEEDED) {
        int*   deg       = (int*)ws;
        int*   cursor    = (int*)(ws + OFF_CUR);
        float* stats     = (float*)(ws + OFF_STAT);
        float* dinv      = (float*)(ws + OFF_DINV);
        int*   row_start = (int*)(ws + OFF_ROW);
        int*   bsum      = (int*)(ws + OFF_BSUM);
        int*   boff      = (int*)(ws + OFF_BOFF);
        int*   csr       = (int*)(ws + OFF_CSR);
        float* h         = (float*)(ws + OFF_H);

        hipMemsetAsync(d_ws, 0, OFF_STAT + 512, stream);  // deg, cursor, stats

        k_deg_int   <<<2048, 256, 0, stream>>>(dst, deg);
        k_scan_block<<<NB_SCAN, 256, 0, stream>>>(deg, bsum);
        k_scan_top  <<<1, 512, 0, stream>>>(bsum, boff);
        k_scan_write<<<NB_SCAN, 256, 0, stream>>>(deg, boff, row_start, dinv);
        k_fill      <<<2048, 256, 0, stream>>>(src, dst, row_start, cursor, csr);
        k_gemm2     <<<GEMM_GRID, 256, 0, stream>>>(x, W, xw);
        k_gather    <<<2048, 256, 0, stream>>>(csr, row_start, dinv,
                                               (const float4*)xw, b, (float4*)h, stats);
        k_final4    <<<2048, 256, 0, stream>>>((const float4*)h, stats, bnw, bnb,
                                               (float4*)out);
    } else {
        // fallback: atomic scatter
        const size_t DEG_BYTES = SZ_I;
        const size_t AGG_BYTES = (size_t)N_NODES * C_DIM * 4;
        float* deg   = (float*)ws;
        float* agg   = (float*)(ws + DEG_BYTES);
        float* stats = (float*)(ws + DEG_BYTES + AGG_BYTES);

        hipMemsetAsync(d_ws, 0, DEG_BYTES + AGG_BYTES + 512, stream);
        k_deg_f  <<<2048, 256, 0, stream>>>(dst, deg);
        k_dinv_f <<<(N_NODES + 255) / 256, 256, 0, stream>>>(deg);
        k_gemm2  <<<GEMM_GRID, 256, 0, stream>>>(x, W, xw);
        k_scatter<<<4096, 256, 0, stream>>>(src, dst, deg, xw, agg);
        k_bnstats<<<2048, 256, 0, stream>>>(agg, xw, deg, b, stats);
        k_final4 <<<2048, 256, 0, stream>>>((const float4*)agg, stats, bnw, bnb,
                                            (float4*)out);
    }
}